// Round 5
// baseline (213.952 us; speedup 1.0000x reference)
//
#include <hip/hip_runtime.h>

#define HW    16384   // 128*128
#define Wh    128
#define Cin   64
#define C2    32
#define HW4   4096    // 64*64

typedef short short8 __attribute__((ext_vector_type(8)));   // 8 bf16 = 4 VGPRs
typedef float float4v __attribute__((ext_vector_type(4)));

#define LOG2E 1.44269504f
#define OFFE  43.2808512f   // 30*log2(e): exp(s-30) == exp2(s*LOG2E - OFFE)

__device__ __forceinline__ unsigned pack2bf16(float lo, float hi) {
  unsigned ul = __builtin_bit_cast(unsigned, lo);
  unsigned uh = __builtin_bit_cast(unsigned, hi);
  ul = (ul + 0x7fffu + ((ul >> 16) & 1u)) >> 16;
  uh = (uh + 0x7fffu + ((uh >> 16) & 1u)) & 0xffff0000u;
  return ul | uh;
}
__device__ __forceinline__ unsigned short f2bf(float f) {
  unsigned u = __builtin_bit_cast(unsigned, f);
  return (unsigned short)((u + 0x7fffu + ((u >> 16) & 1u)) >> 16);
}

// ---------------------------------------------------------------------------
// Kernel 1: FUSED theta + phi + g conv (+2x2 maxpool for phi/g).
// Block = 256 threads = 64 pooled pixels (one pooled row) x 2x2 full-res.
// og (8-channel group) from blockIdx.y -> all weight reads are s_load.
// Outputs: Q bf16 [b][p][32] (theta, pre-scaled by log2e),
//          K bf16 [b][key][32] (phi, pooled),
//          Vt bf16 [b][ch][4096] (g, pooled, transposed, in-tile slot
//          permutation key k<16 -> 2k else 2(k-16)+1), written COALESCED
//          via an LDS transpose (was the 8x scattered-2B-store hotspot).
// ---------------------------------------------------------------------------
__global__ __launch_bounds__(256) void conv_qkv_kern(
    const float* __restrict__ x,
    const float* __restrict__ wt, const float* __restrict__ bt,
    const float* __restrict__ wp, const float* __restrict__ bp,
    const float* __restrict__ wg, const float* __restrict__ bg,
    unsigned short* __restrict__ Q, unsigned short* __restrict__ K,
    unsigned short* __restrict__ Vt) {
  __shared__ unsigned short smV[8][64];
  int tid = threadIdx.x;
  int og = blockIdx.y, b = blockIdx.z;
  int pp = blockIdx.x * 64 + (tid >> 2);         // pooled pixel
  int i = pp >> 6, jc = pp & 63;
  int row = 2 * i + ((tid >> 1) & 1);
  int col = 2 * jc + (tid & 1);
  int p = row * Wh + col;                        // full-res pixel
  const float* xb = x + (size_t)b * Cin * HW + p;
  const float* wto = wt + og * 8 * Cin;          // uniform -> s_load
  const float* wpo = wp + og * 8 * Cin;
  const float* wgo = wg + og * 8 * Cin;
  float aT[8], aP[8], aG[8];
#pragma unroll
  for (int o = 0; o < 8; ++o) {
    aT[o] = bt[og * 8 + o]; aP[o] = bp[og * 8 + o]; aG[o] = bg[og * 8 + o];
  }
  for (int c = 0; c < Cin; ++c) {
    float xv = xb[(size_t)c * HW];               // 2 rows x 128 cols: coalesced
#pragma unroll
    for (int o = 0; o < 8; ++o) {
      aT[o] = fmaf(wto[o * Cin + c], xv, aT[o]);
      aP[o] = fmaf(wpo[o * Cin + c], xv, aP[o]);
      aG[o] = fmaf(wgo[o * Cin + c], xv, aG[o]);
    }
  }
  // theta -> Q (pre-scaled by log2e)
  {
    uint4 up;
    up.x = pack2bf16(aT[0] * LOG2E, aT[1] * LOG2E);
    up.y = pack2bf16(aT[2] * LOG2E, aT[3] * LOG2E);
    up.z = pack2bf16(aT[4] * LOG2E, aT[5] * LOG2E);
    up.w = pack2bf16(aT[6] * LOG2E, aT[7] * LOG2E);
    *(uint4*)(Q + ((size_t)b * HW + p) * C2 + og * 8) = up;
  }
  // 2x2 maxpool across lane-mates {4j..4j+3}
#pragma unroll
  for (int o = 0; o < 8; ++o) {
    aP[o] = fmaxf(aP[o], __shfl_xor(aP[o], 1));
    aP[o] = fmaxf(aP[o], __shfl_xor(aP[o], 2));
    aG[o] = fmaxf(aG[o], __shfl_xor(aG[o], 1));
    aG[o] = fmaxf(aG[o], __shfl_xor(aG[o], 2));
  }
  if ((tid & 3) == 0) {
    uint4 up;
    up.x = pack2bf16(aP[0], aP[1]); up.y = pack2bf16(aP[2], aP[3]);
    up.z = pack2bf16(aP[4], aP[5]); up.w = pack2bf16(aP[6], aP[7]);
    *(uint4*)(K + ((size_t)b * HW4 + pp) * C2 + og * 8) = up;
    int loc = pp & 31, tl = (pp >> 5) & 1;
    int slot = (loc < 16) ? (2 * loc) : (2 * (loc - 16) + 1);
#pragma unroll
    for (int o = 0; o < 8; ++o) smV[o][tl * 32 + slot] = f2bf(aG[o]);
  }
  __syncthreads();
  // coalesced V store: thread t -> channel t>>5, col pair t&31 (dword)
  {
    int ch = tid >> 5, cp = tid & 31;
    unsigned v = ((unsigned*)smV)[ch * 32 + cp];
    *(unsigned*)(Vt + (size_t)b * C2 * HW4 + (size_t)(og * 8 + ch) * HW4 +
                 blockIdx.x * 64 + 2 * cp) = v;
  }
}

// ---------------------------------------------------------------------------
// Kernel 2: MFMA flash attention, 4-way key split, 2 Q-frags (32 rows)/wave.
// Block 256 = 4 waves, all on the same 32 rows; wave wv -> keys wv*1024..+1023.
// Per 32-key tile: 4 QK MFMA (C-init=-OFFE; Q pre-scaled by log2e), exp2
// straight off MFMA, v_perm RTZ pack, in-wave LDS C->A roundtrip (double-
// buffered, no barriers in loop), 4 PV MFMA + 2 ones-MFMA (row sums).
// Key quarters merged through LDS (overlaid on the P buffer; 2 barriers).
// ---------------------------------------------------------------------------
__global__ __launch_bounds__(256, 6) void attn_mfma_kern(
    const unsigned short* __restrict__ Qb, const unsigned short* __restrict__ Kb,
    const unsigned short* __restrict__ Vt, float* __restrict__ Y) {
  __shared__ unsigned smem[5120];   // 20480 B: plds[2][4][640]; merge overlays
  int lane = threadIdx.x & 63;
  int wv = threadIdx.x >> 6;
  int quad = lane >> 4, l16 = lane & 15;
  int b = blockIdx.y;
  int qrow0 = blockIdx.x * 32;

  short8 qf0 = *(const short8*)(Qb + (((size_t)b * HW + qrow0 + l16) * C2 + quad * 8));
  short8 qf1 = *(const short8*)(Qb + (((size_t)b * HW + qrow0 + 16 + l16) * C2 + quad * 8));
  const unsigned short* kb = Kb + ((size_t)b * HW4 + wv * 1024) * C2;
  const unsigned short* vb = Vt + (size_t)b * C2 * HW4 + wv * 1024;

  short8 ones;
#pragma unroll
  for (int i = 0; i < 8; ++i) ones[i] = (short)0x3F80;  // bf16 1.0

  float4v z = {0.f, 0.f, 0.f, 0.f};
  float4v y00 = z, y10 = z, y20 = z, y01 = z, y11 = z, y21 = z;
  float4v moff = {-OFFE, -OFFE, -OFFE, -OFFE};

  for (int t = 0; t < 32; ++t) {
    const unsigned short* kt = kb + (size_t)t * 32 * C2;
    const unsigned short* vt = vb + (size_t)t * 32;
    short8 kfa = *(const short8*)(kt + (size_t)l16 * C2 + quad * 8);
    short8 kfb = *(const short8*)(kt + (size_t)(16 + l16) * C2 + quad * 8);
    short8 vfa = *(const short8*)(vt + (size_t)l16 * HW4 + quad * 8);
    short8 vfb = *(const short8*)(vt + (size_t)(16 + l16) * HW4 + quad * 8);

    float4v s0 = __builtin_amdgcn_mfma_f32_16x16x32_bf16(qf0, kfa, moff, 0, 0, 0);
    float4v s1 = __builtin_amdgcn_mfma_f32_16x16x32_bf16(qf0, kfb, moff, 0, 0, 0);
    float4v s2 = __builtin_amdgcn_mfma_f32_16x16x32_bf16(qf1, kfa, moff, 0, 0, 0);
    float4v s3 = __builtin_amdgcn_mfma_f32_16x16x32_bf16(qf1, kfb, moff, 0, 0, 0);

    unsigned* pb = &smem[(t & 1) * 2560 + wv * 640];
#pragma unroll
    for (int r = 0; r < 4; ++r) {
      float a0 = __builtin_amdgcn_exp2f(s0[r]);
      float a1 = __builtin_amdgcn_exp2f(s1[r]);
      pb[(quad * 4 + r) * 20 + l16] =
          __builtin_amdgcn_perm(__builtin_bit_cast(unsigned, a1),
                                __builtin_bit_cast(unsigned, a0), 0x07060302u);
      float b0 = __builtin_amdgcn_exp2f(s2[r]);
      float b1 = __builtin_amdgcn_exp2f(s3[r]);
      pb[320 + (quad * 4 + r) * 20 + l16] =
          __builtin_amdgcn_perm(__builtin_bit_cast(unsigned, b1),
                                __builtin_bit_cast(unsigned, b0), 0x07060302u);
    }
    short8 pf0 = *(const short8*)&pb[l16 * 20 + quad * 4];
    short8 pf1 = *(const short8*)&pb[320 + l16 * 20 + quad * 4];

    y00 = __builtin_amdgcn_mfma_f32_16x16x32_bf16(pf0, vfa,  y00, 0, 0, 0);
    y10 = __builtin_amdgcn_mfma_f32_16x16x32_bf16(pf0, vfb,  y10, 0, 0, 0);
    y20 = __builtin_amdgcn_mfma_f32_16x16x32_bf16(pf0, ones, y20, 0, 0, 0);
    y01 = __builtin_amdgcn_mfma_f32_16x16x32_bf16(pf1, vfa,  y01, 0, 0, 0);
    y11 = __builtin_amdgcn_mfma_f32_16x16x32_bf16(pf1, vfb,  y11, 0, 0, 0);
    y21 = __builtin_amdgcn_mfma_f32_16x16x32_bf16(pf1, ones, y21, 0, 0, 0);
  }

  // ---- merge the 4 key quarters (merge buffers overlay plds; 2 barriers) ----
  __syncthreads();                               // all plds reads done
  float* smf = (float*)smem;                     // smY: [3][32][33]; smL at 3168
  if (wv > 0) {
    int pi = wv - 1;
#pragma unroll
    for (int r = 0; r < 4; ++r) {
      int lr0 = quad * 4 + r, lr1 = lr0 + 16;
      smf[(pi * 32 + lr0) * 33 + l16]      = y00[r];
      smf[(pi * 32 + lr0) * 33 + 16 + l16] = y10[r];
      smf[(pi * 32 + lr1) * 33 + l16]      = y01[r];
      smf[(pi * 32 + lr1) * 33 + 16 + l16] = y11[r];
      if (l16 == 0) {
        smf[3168 + pi * 32 + lr0] = y20[r];
        smf[3168 + pi * 32 + lr1] = y21[r];
      }
    }
  }
  __syncthreads();
  if (wv == 0) {
#pragma unroll
    for (int r = 0; r < 4; ++r) {
      int lr0 = quad * 4 + r, lr1 = lr0 + 16;
      float a0 = y00[r], a1 = y10[r], c0 = y01[r], c1 = y11[r];
      float l0 = y20[r], l1 = y21[r];
#pragma unroll
      for (int pi = 0; pi < 3; ++pi) {
        a0 += smf[(pi * 32 + lr0) * 33 + l16];
        a1 += smf[(pi * 32 + lr0) * 33 + 16 + l16];
        c0 += smf[(pi * 32 + lr1) * 33 + l16];
        c1 += smf[(pi * 32 + lr1) * 33 + 16 + l16];
        l0 += smf[3168 + pi * 32 + lr0];
        l1 += smf[3168 + pi * 32 + lr1];
      }
      float inv0 = 1.f / l0, inv1 = 1.f / l1;
      size_t row0 = (size_t)b * HW + qrow0 + lr0;
      size_t row1 = (size_t)b * HW + qrow0 + lr1;
      Y[row0 * C2 + l16]      = a0 * inv0;
      Y[row0 * C2 + 16 + l16] = a1 * inv0;
      Y[row1 * C2 + l16]      = c0 * inv1;
      Y[row1 * C2 + 16 + l16] = c1 * inv1;
    }
  }
}

// ---------------------------------------------------------------------------
// Kernel 3: output conv (32->64) + bias + residual; cog from blockIdx.y.
// ---------------------------------------------------------------------------
__global__ __launch_bounds__(256) void conv_out_kern(
    const float* __restrict__ Y, const float* __restrict__ x,
    const float* __restrict__ w, const float* __restrict__ bias,
    float* __restrict__ out) {
  int p = blockIdx.x * 256 + threadIdx.x;
  int cog = blockIdx.y, b = blockIdx.z;
  float y[C2];
  const float4* yp4 = (const float4*)(Y + ((size_t)b * HW + p) * C2);
#pragma unroll
  for (int i = 0; i < 8; ++i) {
    float4 t = yp4[i];
    y[4 * i] = t.x; y[4 * i + 1] = t.y; y[4 * i + 2] = t.z; y[4 * i + 3] = t.w;
  }
  const float* xb = x + (size_t)b * Cin * HW + p;
  float* ob = out + (size_t)b * Cin * HW + p;
#pragma unroll
  for (int i = 0; i < 16; ++i) {
    int co = cog * 16 + i;
    float s = bias[co];
#pragma unroll
    for (int o = 0; o < C2; ++o) s = fmaf(w[co * C2 + o], y[o], s);  // s_load
    ob[(size_t)co * HW] = s + xb[(size_t)co * HW];                   // coalesced
  }
}

// ---------------------------------------------------------------------------
extern "C" void kernel_launch(void* const* d_in, const int* in_sizes, int n_in,
                              void* d_out, int out_size, void* d_ws, size_t ws_size,
                              hipStream_t stream) {
  const float* x       = (const float*)d_in[0];
  const float* w_theta = (const float*)d_in[1];
  const float* b_theta = (const float*)d_in[2];
  const float* w_phi   = (const float*)d_in[3];
  const float* b_phi   = (const float*)d_in[4];
  const float* w_g     = (const float*)d_in[5];
  const float* b_g     = (const float*)d_in[6];
  const float* w_out   = (const float*)d_in[7];
  const float* b_out   = (const float*)d_in[8];
  float* out = (float*)d_out;

  float* Yws = (float*)d_ws;                                   // 8 MB fp32
  unsigned short* Qb = (unsigned short*)(Yws + (size_t)4 * HW * C2);
  unsigned short* Kb = Qb + (size_t)4 * HW * C2;
  unsigned short* Vt = Kb + (size_t)4 * HW4 * C2;

  conv_qkv_kern<<<dim3(64, 4, 4), 256, 0, stream>>>(
      x, w_theta, b_theta, w_phi, b_phi, w_g, b_g, Qb, Kb, Vt);
  attn_mfma_kern<<<dim3(HW / 32, 4), 256, 0, stream>>>(Qb, Kb, Vt, Yws);
  conv_out_kern<<<dim3(HW / 256, 4, 4), 256, 0, stream>>>(Yws, x, w_out, b_out, out);
}

// Round 7
// 195.751 us; speedup vs baseline: 1.0930x; 1.0930x over previous
//
#include <hip/hip_runtime.h>

#define HW    16384   // 128*128
#define Wh    128
#define Cin   64
#define C2    32
#define HW4   4096    // 64*64

typedef short short8 __attribute__((ext_vector_type(8)));     // 8 bf16 = 4 VGPRs
typedef float float4v __attribute__((ext_vector_type(4)));
typedef unsigned uint4v __attribute__((ext_vector_type(4)));

#define LOG2E 1.44269504f
#define OFFE  43.2808512f   // 30*log2(e): exp(s-30) == exp2(s*log2e - OFFE)

__device__ __forceinline__ unsigned pack2bf16(float lo, float hi) {
  unsigned ul = __builtin_bit_cast(unsigned, lo);
  unsigned uh = __builtin_bit_cast(unsigned, hi);
  ul = (ul + 0x7fffu + ((ul >> 16) & 1u)) >> 16;
  uh = (uh + 0x7fffu + ((uh >> 16) & 1u)) & 0xffff0000u;
  return ul | uh;
}
__device__ __forceinline__ unsigned short f2bf(float f) {
  unsigned u = __builtin_bit_cast(unsigned, f);
  return (unsigned short)((u + 0x7fffu + ((u >> 16) & 1u)) >> 16);
}
// RTZ-truncate two fp32 to bf16, lo in [15:0], hi in [31:16]
__device__ __forceinline__ unsigned packtrunc(float lo, float hi) {
  return __builtin_amdgcn_perm(__builtin_bit_cast(unsigned, hi),
                               __builtin_bit_cast(unsigned, lo), 0x07060302u);
}

// ---------------------------------------------------------------------------
// Kernel 0: weight repack. wAll[og][c][24] = {theta(8, x log2e), phi(8), g(8)}
// contiguous per c -> conv inner loop reads 96 B/c via wide s_loads
// (was 24 separate stride-256B s_load_dword -> SMEM-issue bound).
// ---------------------------------------------------------------------------
__global__ __launch_bounds__(256) void repack_w_kern(
    const float* __restrict__ wt, const float* __restrict__ bt,
    const float* __restrict__ wp, const float* __restrict__ bp,
    const float* __restrict__ wg, const float* __restrict__ bg,
    float* __restrict__ wAll, float* __restrict__ bAll) {
  int idx = blockIdx.x * 256 + threadIdx.x;
  if (idx < 6144) {
    int og = idx / 1536, rem = idx % 1536;
    int c = rem / 24, j = rem % 24;
    int o = og * 8 + (j & 7);
    float v;
    if (j < 8)       v = wt[o * Cin + c] * LOG2E;
    else if (j < 16) v = wp[o * Cin + c];
    else             v = wg[o * Cin + c];
    wAll[idx] = v;
  } else if (idx < 6240) {
    int i2 = idx - 6144;
    int og = i2 / 24, j = i2 % 24;
    int o = og * 8 + (j & 7);
    bAll[i2] = (j < 8) ? bt[o] * LOG2E : (j < 16 ? bp[o] : bg[o]);
  }
}

// ---------------------------------------------------------------------------
// Kernel 1: FUSED theta+phi+g conv (+2x2 maxpool for phi/g).
// Outputs: Q bf16 [b][p][32] (pre-scaled by log2e via weights),
//          K bf16 [b][key][32] with per-32-tile ROW PERMUTATION
//            key k -> row ((k&4)<<2) + ((k>>3)<<2) + (k&3)  (Sᵀ-trick),
//          Vt bf16 [b][ch][4096] transposed, natural key order, coalesced
//            dword stores via LDS transpose.
// ---------------------------------------------------------------------------
__global__ __launch_bounds__(256) void conv_qkv_kern(
    const float* __restrict__ x, const float* __restrict__ wAll,
    const float* __restrict__ bAll, unsigned short* __restrict__ Q,
    unsigned short* __restrict__ K, unsigned short* __restrict__ Vt) {
  __shared__ unsigned short smV[8][64];
  int tid = threadIdx.x;
  int og = blockIdx.y, b = blockIdx.z;
  int pp = blockIdx.x * 64 + (tid >> 2);         // pooled pixel
  int i = pp >> 6, jc = pp & 63;
  int row = 2 * i + ((tid >> 1) & 1);
  int col = 2 * jc + (tid & 1);
  int p = row * Wh + col;                        // full-res pixel
  const float* xb = x + (size_t)b * Cin * HW + p;
  const float* wc = wAll + og * 1536;            // uniform -> s_load
  const float* bb = bAll + og * 24;
  float acc[24];
#pragma unroll
  for (int j = 0; j < 24; ++j) acc[j] = bb[j];
  for (int c = 0; c < Cin; ++c) {
    float xv = xb[(size_t)c * HW];               // coalesced (2 rows x 128)
#pragma unroll
    for (int j = 0; j < 24; ++j) acc[j] = fmaf(wc[c * 24 + j], xv, acc[j]);
  }
  // theta -> Q
  {
    uint4 up;
    up.x = pack2bf16(acc[0], acc[1]); up.y = pack2bf16(acc[2], acc[3]);
    up.z = pack2bf16(acc[4], acc[5]); up.w = pack2bf16(acc[6], acc[7]);
    *(uint4*)(Q + ((size_t)b * HW + p) * C2 + og * 8) = up;
  }
  // 2x2 maxpool across lane-mates {4j..4j+3}
  float aP[8], aG[8];
#pragma unroll
  for (int o = 0; o < 8; ++o) {
    float vp = acc[8 + o], vg = acc[16 + o];
    vp = fmaxf(vp, __shfl_xor(vp, 1)); vp = fmaxf(vp, __shfl_xor(vp, 2));
    vg = fmaxf(vg, __shfl_xor(vg, 1)); vg = fmaxf(vg, __shfl_xor(vg, 2));
    aP[o] = vp; aG[o] = vg;
  }
  if ((tid & 3) == 0) {
    int loc = pp & 31, tile = pp >> 5;
    // K row permutation for the S^T trick: perm(k)=((k&4)<<2)+((k>>3)<<2)+(k&3)
    int prow = ((loc & 4) << 2) + ((loc >> 3) << 2) + (loc & 3);
    uint4 up;
    up.x = pack2bf16(aP[0], aP[1]); up.y = pack2bf16(aP[2], aP[3]);
    up.z = pack2bf16(aP[4], aP[5]); up.w = pack2bf16(aP[6], aP[7]);
    *(uint4*)(K + ((size_t)b * HW4 + tile * 32 + prow) * C2 + og * 8) = up;
    int tl = tile & 1;
#pragma unroll
    for (int o = 0; o < 8; ++o) smV[o][tl * 32 + loc] = f2bf(aG[o]);
  }
  __syncthreads();
  // coalesced V store: thread t -> channel t>>5, key-pair t&31 (dword)
  {
    int ch = tid >> 5, cp = tid & 31;
    unsigned v = ((unsigned*)smV)[ch * 32 + cp];
    *(unsigned*)(Vt + (size_t)b * C2 * HW4 + (size_t)(og * 8 + ch) * HW4 +
                 blockIdx.x * 64 + 2 * cp) = v;
  }
}

// ---------------------------------------------------------------------------
// Kernel 2: MFMA flash attention — NO LDS in the main loop.
// S^T trick: compute S^T = K_perm · Q^T. C-layout of S^T puts q on lane&15
// and key on the reg index, so exp2 + pairwise pack yields the PV A-fragment
// entirely in registers. K rows permuted so lane's 8 packed values are
// exactly keys quad*8..+7 in order. V is plain-transposed [ch][key].
// Block 256 = 4 waves = 4 key quarters of the same 32 q-rows (2 frags/wave).
// l0/l1 are per-quad partials (8 keys/tile each) -> MUST be reduced across
// the quad bits (lane bits 4..5) before use — that was the R6 bug.
// ---------------------------------------------------------------------------
__global__ __launch_bounds__(256, 6) void attn_mfma_kern(
    const unsigned short* __restrict__ Qb, const unsigned short* __restrict__ Kb,
    const unsigned short* __restrict__ Vt, float* __restrict__ Y) {
  __shared__ float smY[3][32][33];
  __shared__ float smL[4][32];
  int lane = threadIdx.x & 63;
  int wv = threadIdx.x >> 6;
  int quad = lane >> 4, l16 = lane & 15;
  int b = blockIdx.y;
  int qrow0 = blockIdx.x * 32;

  // Q as B-fragment (B[k=c][n=q]): lane l16 = q, holds c = quad*8..+7
  short8 qf0 = *(const short8*)(Qb + ((size_t)b * HW + qrow0 + l16) * C2 + quad * 8);
  short8 qf1 = *(const short8*)(Qb + ((size_t)b * HW + qrow0 + 16 + l16) * C2 + quad * 8);
  const unsigned short* kb = Kb + ((size_t)b * HW4 + wv * 1024) * C2;
  const unsigned short* vb = Vt + (size_t)b * C2 * HW4 + wv * 1024;

  float4v z = {0.f, 0.f, 0.f, 0.f};
  float4v y00 = z, y10 = z, y01 = z, y11 = z;
  float l0 = 0.f, l1 = 0.f;
  float4v moff = {-OFFE, -OFFE, -OFFE, -OFFE};

#pragma unroll 2
  for (int t = 0; t < 32; ++t) {
    const unsigned short* kt = kb + (size_t)t * 32 * C2;
    const unsigned short* vt = vb + t * 32;
    // K as A-fragment (A[m=permrow][k=c]): lane l16 = permuted row
    short8 ka = *(const short8*)(kt + (size_t)l16 * C2 + quad * 8);
    short8 kh = *(const short8*)(kt + (size_t)(16 + l16) * C2 + quad * 8);
    // V as B-fragment (B[k=key][n=ch]): lane l16 = ch, keys quad*8..+7
    short8 va = *(const short8*)(vt + (size_t)l16 * HW4 + quad * 8);
    short8 vh = *(const short8*)(vt + (size_t)(16 + l16) * HW4 + quad * 8);

    // S^T = K_perm · Q^T  (C-init = -OFFE)
    float4v s00 = __builtin_amdgcn_mfma_f32_16x16x32_bf16(ka, qf0, moff, 0, 0, 0);
    float4v s10 = __builtin_amdgcn_mfma_f32_16x16x32_bf16(kh, qf0, moff, 0, 0, 0);
    float4v s01 = __builtin_amdgcn_mfma_f32_16x16x32_bf16(ka, qf1, moff, 0, 0, 0);
    float4v s11 = __builtin_amdgcn_mfma_f32_16x16x32_bf16(kh, qf1, moff, 0, 0, 0);

    // frag0: exp2 -> pack as PV A-fragment (keys quad*8..+7 in order)
    {
      float e0 = __builtin_amdgcn_exp2f(s00[0]), e1 = __builtin_amdgcn_exp2f(s00[1]);
      float e2 = __builtin_amdgcn_exp2f(s00[2]), e3 = __builtin_amdgcn_exp2f(s00[3]);
      float f0 = __builtin_amdgcn_exp2f(s10[0]), f1 = __builtin_amdgcn_exp2f(s10[1]);
      float f2 = __builtin_amdgcn_exp2f(s10[2]), f3 = __builtin_amdgcn_exp2f(s10[3]);
      l0 += ((e0 + e1) + (e2 + e3)) + ((f0 + f1) + (f2 + f3));
      uint4v d = {packtrunc(e0, e1), packtrunc(e2, e3),
                  packtrunc(f0, f1), packtrunc(f2, f3)};
      short8 pf0 = __builtin_bit_cast(short8, d);
      y00 = __builtin_amdgcn_mfma_f32_16x16x32_bf16(pf0, va, y00, 0, 0, 0);
      y10 = __builtin_amdgcn_mfma_f32_16x16x32_bf16(pf0, vh, y10, 0, 0, 0);
    }
    // frag1
    {
      float e0 = __builtin_amdgcn_exp2f(s01[0]), e1 = __builtin_amdgcn_exp2f(s01[1]);
      float e2 = __builtin_amdgcn_exp2f(s01[2]), e3 = __builtin_amdgcn_exp2f(s01[3]);
      float f0 = __builtin_amdgcn_exp2f(s11[0]), f1 = __builtin_amdgcn_exp2f(s11[1]);
      float f2 = __builtin_amdgcn_exp2f(s11[2]), f3 = __builtin_amdgcn_exp2f(s11[3]);
      l1 += ((e0 + e1) + (e2 + e3)) + ((f0 + f1) + (f2 + f3));
      uint4v d = {packtrunc(e0, e1), packtrunc(e2, e3),
                  packtrunc(f0, f1), packtrunc(f2, f3)};
      short8 pf1 = __builtin_bit_cast(short8, d);
      y01 = __builtin_amdgcn_mfma_f32_16x16x32_bf16(pf1, va, y01, 0, 0, 0);
      y11 = __builtin_amdgcn_mfma_f32_16x16x32_bf16(pf1, vh, y11, 0, 0, 0);
    }
  }

  // l0/l1 are per-quad partial row sums (q = l16): reduce across quad bits
  // (lane bits 4 and 5) to get the full row sum on every lane.  [R6 bugfix]
  l0 += __shfl_xor(l0, 16);  l0 += __shfl_xor(l0, 32);
  l1 += __shfl_xor(l1, 16);  l1 += __shfl_xor(l1, 32);

  if (quad == 0) { smL[wv][l16] = l0; smL[wv][16 + l16] = l1; }
  if (wv > 0) {
    int pi = wv - 1;
#pragma unroll
    for (int r = 0; r < 4; ++r) {
      int lr0 = quad * 4 + r, lr1 = lr0 + 16;
      smY[pi][lr0][l16] = y00[r];  smY[pi][lr0][16 + l16] = y10[r];
      smY[pi][lr1][l16] = y01[r];  smY[pi][lr1][16 + l16] = y11[r];
    }
  }
  __syncthreads();
  if (wv == 0) {
#pragma unroll
    for (int r = 0; r < 4; ++r) {
      int lr0 = quad * 4 + r, lr1 = lr0 + 16;
      float a0 = y00[r] + smY[0][lr0][l16] + smY[1][lr0][l16] + smY[2][lr0][l16];
      float a1 = y10[r] + smY[0][lr0][16 + l16] + smY[1][lr0][16 + l16] + smY[2][lr0][16 + l16];
      float c0 = y01[r] + smY[0][lr1][l16] + smY[1][lr1][l16] + smY[2][lr1][l16];
      float c1 = y11[r] + smY[0][lr1][16 + l16] + smY[1][lr1][16 + l16] + smY[2][lr1][16 + l16];
      float L0 = smL[0][lr0] + smL[1][lr0] + smL[2][lr0] + smL[3][lr0];
      float L1 = smL[0][lr1] + smL[1][lr1] + smL[2][lr1] + smL[3][lr1];
      float inv0 = 1.f / L0, inv1 = 1.f / L1;
      size_t row0 = (size_t)b * HW + qrow0 + lr0;
      size_t row1 = (size_t)b * HW + qrow0 + lr1;
      Y[row0 * C2 + l16]      = a0 * inv0;
      Y[row0 * C2 + 16 + l16] = a1 * inv0;
      Y[row1 * C2 + l16]      = c0 * inv1;
      Y[row1 * C2 + 16 + l16] = c1 * inv1;
    }
  }
}

// ---------------------------------------------------------------------------
// Kernel 3: output conv (32->64) + bias + residual; cog from blockIdx.y.
// ---------------------------------------------------------------------------
__global__ __launch_bounds__(256) void conv_out_kern(
    const float* __restrict__ Y, const float* __restrict__ x,
    const float* __restrict__ w, const float* __restrict__ bias,
    float* __restrict__ out) {
  int p = blockIdx.x * 256 + threadIdx.x;
  int cog = blockIdx.y, b = blockIdx.z;
  float y[C2];
  const float4* yp4 = (const float4*)(Y + ((size_t)b * HW + p) * C2);
#pragma unroll
  for (int i = 0; i < 8; ++i) {
    float4 t = yp4[i];
    y[4 * i] = t.x; y[4 * i + 1] = t.y; y[4 * i + 2] = t.z; y[4 * i + 3] = t.w;
  }
  const float* xb = x + (size_t)b * Cin * HW + p;
  float* ob = out + (size_t)b * Cin * HW + p;
#pragma unroll
  for (int i = 0; i < 16; ++i) {
    int co = cog * 16 + i;
    float s = bias[co];
#pragma unroll
    for (int o = 0; o < C2; ++o) s = fmaf(w[co * C2 + o], y[o], s);
    ob[(size_t)co * HW] = s + xb[(size_t)co * HW];
  }
}

// ---------------------------------------------------------------------------
extern "C" void kernel_launch(void* const* d_in, const int* in_sizes, int n_in,
                              void* d_out, int out_size, void* d_ws, size_t ws_size,
                              hipStream_t stream) {
  const float* x       = (const float*)d_in[0];
  const float* w_theta = (const float*)d_in[1];
  const float* b_theta = (const float*)d_in[2];
  const float* w_phi   = (const float*)d_in[3];
  const float* b_phi   = (const float*)d_in[4];
  const float* w_g     = (const float*)d_in[5];
  const float* b_g     = (const float*)d_in[6];
  const float* w_out   = (const float*)d_in[7];
  const float* b_out   = (const float*)d_in[8];
  float* out = (float*)d_out;

  float* Yws = (float*)d_ws;                                   // 8 MB fp32
  unsigned short* Qb = (unsigned short*)(Yws + (size_t)4 * HW * C2);
  unsigned short* Kb = Qb + (size_t)4 * HW * C2;
  unsigned short* Vt = Kb + (size_t)4 * HW4 * C2;
  float* wAll = (float*)(Vt + (size_t)4 * HW4 * C2);           // 6144 f
  float* bAll = wAll + 6144;                                   // 96 f

  repack_w_kern<<<25, 256, 0, stream>>>(w_theta, b_theta, w_phi, b_phi,
                                        w_g, b_g, wAll, bAll);
  conv_qkv_kern<<<dim3(64, 4, 4), 256, 0, stream>>>(x, wAll, bAll, Qb, Kb, Vt);
  attn_mfma_kern<<<dim3(HW / 32, 4), 256, 0, stream>>>(Qb, Kb, Vt, Yws);
  conv_out_kern<<<dim3(64, 4, 4), 256, 0, stream>>>(Yws, x, w_out, b_out, out);
}